// Round 1
// 327.749 us; speedup vs baseline: 1.0361x; 1.0361x over previous
//
#include <hip/hip_runtime.h>

// Monarch block-diag: out[b, s*64+l] = sum_r w2[l,s,r] * sum_p x[b, r*64+p] * w1[r,l,p]
// B=8192, N=4096, blocks 64. fp32 in/out; bf16 MFMA compute.
//
// Prologue kernel: w1,w2 fp32 -> bf16 into d_ws (1 MiB).
// Main kernel: 512 thr (8 waves), b-tile 16, grid 512.
//   - x fp32 read ONCE, converted to persistent bf16 A-frags in registers (qc-invariant).
//   - 4 q-chunks of 16: stage-1 (waves split k, 8 each) -> Y[16b][16q][64k] bf16 in 32 KiB
//     swizzled LDS; stage-2 (waves split l-group x s-half) MFMA vs bf16 w2.
//   - NEW: epilogue stages results in a 64 KiB fp32 LDS buffer O[16b][64s][16l]
//     (aliases Y, which is dead by then) and re-reads it so each 64-B output chunk
//     out[b][s*64+qc*16..+16] is written by 4 adjacent lanes of ONE store instruction
//     -> full-sector HBM writes, kills the 2.8x write amplification of the old
//     16-B-per-lane stride-256B store pattern. Nontemporal stores keep x L3-resident.

typedef __bf16 bf16x8 __attribute__((ext_vector_type(8)));
typedef float  float4v __attribute__((ext_vector_type(4)));

__global__ __launch_bounds__(256)
void cvt_weights(const float* __restrict__ w1, const float* __restrict__ w2,
                 __bf16* __restrict__ wb) {
    const int i = (blockIdx.x * 256 + threadIdx.x) * 8;  // grid 128 -> i < 262144
    float4v a = *(const float4v*)(w1 + i);
    float4v b = *(const float4v*)(w1 + i + 4);
    bf16x8 v;
    v[0]=(__bf16)a[0]; v[1]=(__bf16)a[1]; v[2]=(__bf16)a[2]; v[3]=(__bf16)a[3];
    v[4]=(__bf16)b[0]; v[5]=(__bf16)b[1]; v[6]=(__bf16)b[2]; v[7]=(__bf16)b[3];
    *(bf16x8*)(wb + i) = v;
    a = *(const float4v*)(w2 + i);
    b = *(const float4v*)(w2 + i + 4);
    v[0]=(__bf16)a[0]; v[1]=(__bf16)a[1]; v[2]=(__bf16)a[2]; v[3]=(__bf16)a[3];
    v[4]=(__bf16)b[0]; v[5]=(__bf16)b[1]; v[6]=(__bf16)b[2]; v[7]=(__bf16)b[3];
    *(bf16x8*)(wb + 262144 + i) = v;
}

__global__ __launch_bounds__(512, 4)
void monarch_fused(const float* __restrict__ x,
                   const __bf16* __restrict__ w1b,
                   const __bf16* __restrict__ w2b,
                   float* __restrict__ out)
{
    // smem union:
    //   Y: [b(16)][q(16)][kchunk(8) xor-swizzled][elem(8)] bf16 = 32 KiB (first half)
    //   O: [b(16)][s(64)][slot(4) xor-swizzled][li(4)] fp32 = 64 KiB (whole buffer;
    //      only live AFTER stage-2 reads of Y complete, so aliasing is safe)
    __shared__ __align__(16) unsigned char smem[65536];
    __bf16* Y = (__bf16*)smem;
    float*  O = (float*)smem;

    const int tid  = threadIdx.x;
    const int wid  = tid >> 6;      // 0..7
    const int lane = tid & 63;
    const int m    = lane & 15;     // MFMA: A-M / B-N / D-col index
    const int quad = lane >> 4;     // MFMA: A/B K-group, D row-group
    const int b0   = blockIdx.x * 16;

    // ---- preload x as bf16 A-frags: k = wid*8 + j, kk = h*32 + quad*8 + e ----
    bf16x8 xa[8][2];
    {
        const float* xp = x + (long)(b0 + m) * 4096 + wid * 512 + quad * 8;
        #pragma unroll
        for (int j = 0; j < 8; ++j) {
            #pragma unroll
            for (int h = 0; h < 2; ++h) {
                float4v lo = *(const float4v*)(xp + j * 64 + h * 32);
                float4v hi = *(const float4v*)(xp + j * 64 + h * 32 + 4);
                bf16x8 v;
                v[0]=(__bf16)lo[0]; v[1]=(__bf16)lo[1]; v[2]=(__bf16)lo[2]; v[3]=(__bf16)lo[3];
                v[4]=(__bf16)hi[0]; v[5]=(__bf16)hi[1]; v[6]=(__bf16)hi[2]; v[7]=(__bf16)hi[3];
                xa[j][h] = v;
            }
        }
    }

    const int lg = wid >> 1;  // l-group (4 l each)
    const int sh = wid & 1;   // s-half (2 s-tiles each)

    for (int qc = 0; qc < 4; ++qc) {
        // ---- stage 1: Y[b][q in chunk][k] ; wave handles k in [wid*8, wid*8+8) ----
        float4v acc[8];
        #pragma unroll
        for (int j = 0; j < 8; ++j) {
            const int k = wid * 8 + j;
            const __bf16* w1p = w1b + ((k * 64 + qc * 16 + m) * 64) + quad * 8;
            bf16x8 bb0 = *(const bf16x8*)(w1p);
            bf16x8 bb1 = *(const bf16x8*)(w1p + 32);
            float4v c = {0.f, 0.f, 0.f, 0.f};
            c = __builtin_amdgcn_mfma_f32_16x16x32_bf16(xa[j][0], bb0, c, 0, 0, 0);
            c = __builtin_amdgcn_mfma_f32_16x16x32_bf16(xa[j][1], bb1, c, 0, 0, 0);
            acc[j] = c;
        }

        __syncthreads();  // previous chunk's O-phase LDS reads complete (no-op at qc=0)

        // D: lane holds D[b = quad*4+reg][q = qc*16+m], value acc[j][reg] for k=wid*8+j.
        #pragma unroll
        for (int reg = 0; reg < 4; ++reg) {
            const int bl = quad * 4 + reg;
            const int cs = wid ^ (m & 7) ^ (bl & 7);
            bf16x8 v;
            #pragma unroll
            for (int j = 0; j < 8; ++j) v[j] = (__bf16)acc[j][reg];
            *(bf16x8*)(&Y[((bl * 16 + m) * 8 + cs) * 8]) = v;
        }
        __syncthreads();

        // ---- stage 2: l = qc*16 + lg*4 + li ; s-tiles sh*2+st ----
        float4v acc2[4][2];
        #pragma unroll
        for (int li = 0; li < 4; ++li)
            #pragma unroll
            for (int st = 0; st < 2; ++st) acc2[li][st] = (float4v){0.f, 0.f, 0.f, 0.f};

        #pragma unroll
        for (int h = 0; h < 2; ++h) {
            #pragma unroll
            for (int li = 0; li < 4; ++li) {
                const int ll = lg * 4 + li;
                const int l  = qc * 16 + ll;
                const int kc = h * 4 + quad;
                const int cs = kc ^ (ll & 7) ^ (m & 7);
                // A2[b = m][r = h*32 + quad*8 + e] = Y[b][ll][r]
                bf16x8 a2 = *(const bf16x8*)(&Y[((m * 16 + ll) * 8 + cs) * 8]);
                const __bf16* w2p = w2b + (l * 64) * 64 + h * 32 + quad * 8;
                #pragma unroll
                for (int st = 0; st < 2; ++st) {
                    const int s = (sh * 2 + st) * 16 + m;
                    bf16x8 b2 = *(const bf16x8*)(w2p + s * 64);
                    acc2[li][st] = __builtin_amdgcn_mfma_f32_16x16x32_bf16(a2, b2, acc2[li][st], 0, 0, 0);
                }
            }
        }

        __syncthreads();  // all waves done reading Y before O overwrites it

        // ---- O-stage write: lane holds out2[b=b0+quad*4+reg][l=qc*16+lg*4+li][s=(sh*2+st)*16+m]
        // O dword addr = bl*1024 + s*16 + slot*4 + li, slot = lg ^ ((s>>1)&3) ^ (bl&3).
        // Banks: (s&1)*16 + slot*4 -> each of 32 banks gets exactly 8 dwords/wave-instr
        // (the b128 minimum) -> conflict-free.
        #pragma unroll
        for (int st = 0; st < 2; ++st) {
            const int s = (sh * 2 + st) * 16 + m;
            #pragma unroll
            for (int reg = 0; reg < 4; ++reg) {
                const int bl = quad * 4 + reg;
                const int slot = lg ^ ((s >> 1) & 3) ^ (bl & 3);
                float4v v;
                #pragma unroll
                for (int li = 0; li < 4; ++li) v[li] = acc2[li][st][reg];
                *(float4v*)(&O[(bl * 64 + s) * 16 + slot * 4]) = v;
            }
        }
        __syncthreads();

        // ---- O-stage read + coalesced global store: 8 phases x 512 thr x float4 = 64 KiB.
        // Wave = 16 consecutive s for one bl; 4 adjacent lanes fully cover each 64-B
        // out chunk out[b][s*64+qc*16..+16] in ONE instruction -> full-sector writes.
        #pragma unroll
        for (int ph = 0; ph < 8; ++ph) {
            const int g     = ph * 512 + tid;
            const int lanef = g & 3;
            const int chunk = g >> 2;        // 0..1023
            const int s     = chunk & 63;
            const int bl    = chunk >> 6;    // 0..15
            const int slot  = lanef ^ ((s >> 1) & 3) ^ (bl & 3);
            float4v v = *(const float4v*)(&O[(bl * 64 + s) * 16 + slot * 4]);
            float* dst = out + (long)(b0 + bl) * 4096 + s * 64 + qc * 16 + lanef * 4;
            __builtin_nontemporal_store(v, (float4v*)dst);
        }
    }
}

extern "C" void kernel_launch(void* const* d_in, const int* in_sizes, int n_in,
                              void* d_out, int out_size, void* d_ws, size_t ws_size,
                              hipStream_t stream) {
    const float* x  = (const float*)d_in[0];
    const float* w1 = (const float*)d_in[1];
    const float* w2 = (const float*)d_in[2];
    float* out = (float*)d_out;
    __bf16* wb = (__bf16*)d_ws;   // w1b at [0, 262144), w2b at [262144, 524288)

    hipLaunchKernelGGL(cvt_weights, dim3(128), dim3(256), 0, stream, w1, w2, wb);
    hipLaunchKernelGGL(monarch_fused, dim3(8192 / 16), dim3(512), 0, stream,
                       x, wb, wb + 262144, out);
}

// Round 2
// 324.948 us; speedup vs baseline: 1.0450x; 1.0086x over previous
//
#include <hip/hip_runtime.h>

// Monarch block-diag: out[b, s*64+l] = sum_r w2[l,s,r] * sum_p x[b, r*64+p] * w1[r,l,p]
// B=8192, N=4096, blocks 64. fp32 in/out; bf16 MFMA compute.
//
// Prologue kernel: w1,w2 fp32 -> bf16 into d_ws (1 MiB).
// Main kernel: 512 thr (8 waves), b-tile 16, grid 512.
//   - x fp32 read ONCE, converted to persistent bf16 A-frags in registers (qc-invariant).
//   - q-chunks processed in PAIRS (qp = 2 chunks of 16 q each): stage-1 -> Y bf16 LDS,
//     stage-2 -> registers, for qi=0,1; then an epilogue writes BOTH chunks at once so
//     each global-store instruction covers a FULL 128-B L2 line (out[b][s*64+qp*32..+32]).
//     Round-1 evidence: 64-B chunk stores left lines half-dirty -> evicted between qc's
//     -> 1.84x write amplification + 67 MB RMW merge-fetches. Full-line stores kill both.
//   - O epilogue buffer [16b][32 s-slot][32 l] fp32 = 64 KiB aliases Y (dead by then);
//     XOR swizzle phys4 = ((qi<<2)|lg)^(m&7) gives exactly 8 dwords/bank on write and
//     read phases (b128 minimum, conflict-free).

typedef __bf16 bf16x8 __attribute__((ext_vector_type(8)));
typedef float  float4v __attribute__((ext_vector_type(4)));

__global__ __launch_bounds__(256)
void cvt_weights(const float* __restrict__ w1, const float* __restrict__ w2,
                 __bf16* __restrict__ wb) {
    const int i = (blockIdx.x * 256 + threadIdx.x) * 8;  // grid 128 -> i < 262144
    float4v a = *(const float4v*)(w1 + i);
    float4v b = *(const float4v*)(w1 + i + 4);
    bf16x8 v;
    v[0]=(__bf16)a[0]; v[1]=(__bf16)a[1]; v[2]=(__bf16)a[2]; v[3]=(__bf16)a[3];
    v[4]=(__bf16)b[0]; v[5]=(__bf16)b[1]; v[6]=(__bf16)b[2]; v[7]=(__bf16)b[3];
    *(bf16x8*)(wb + i) = v;
    a = *(const float4v*)(w2 + i);
    b = *(const float4v*)(w2 + i + 4);
    v[0]=(__bf16)a[0]; v[1]=(__bf16)a[1]; v[2]=(__bf16)a[2]; v[3]=(__bf16)a[3];
    v[4]=(__bf16)b[0]; v[5]=(__bf16)b[1]; v[6]=(__bf16)b[2]; v[7]=(__bf16)b[3];
    *(bf16x8*)(wb + 262144 + i) = v;
}

__global__ __launch_bounds__(512, 4)
void monarch_fused(const float* __restrict__ x,
                   const __bf16* __restrict__ w1b,
                   const __bf16* __restrict__ w2b,
                   float* __restrict__ out)
{
    // smem union:
    //   Y: [b(16)][q(16)][kchunk(8) xor-swizzled][elem(8)] bf16 = 32 KiB (first half)
    //   O: [b(16)][slot(32)][phys-lp(32) xor-swizzled] fp32 = 64 KiB (whole buffer;
    //      only live AFTER stage-2 reads of Y complete, so aliasing is safe)
    __shared__ __align__(16) unsigned char smem[65536];
    __bf16* Y = (__bf16*)smem;
    float*  O = (float*)smem;

    const int tid  = threadIdx.x;
    const int wid  = tid >> 6;      // 0..7
    const int lane = tid & 63;
    const int m    = lane & 15;     // MFMA: A-M / B-N / D-col index
    const int quad = lane >> 4;     // MFMA: A/B K-group, D row-group
    const int b0   = blockIdx.x * 16;

    // ---- preload x as bf16 A-frags: k = wid*8 + j, kk = h*32 + quad*8 + e ----
    bf16x8 xa[8][2];
    {
        const float* xp = x + (long)(b0 + m) * 4096 + wid * 512 + quad * 8;
        #pragma unroll
        for (int j = 0; j < 8; ++j) {
            #pragma unroll
            for (int h = 0; h < 2; ++h) {
                float4v lo = *(const float4v*)(xp + j * 64 + h * 32);
                float4v hi = *(const float4v*)(xp + j * 64 + h * 32 + 4);
                bf16x8 v;
                v[0]=(__bf16)lo[0]; v[1]=(__bf16)lo[1]; v[2]=(__bf16)lo[2]; v[3]=(__bf16)lo[3];
                v[4]=(__bf16)hi[0]; v[5]=(__bf16)hi[1]; v[6]=(__bf16)hi[2]; v[7]=(__bf16)hi[3];
                xa[j][h] = v;
            }
        }
    }

    const int lg = wid >> 1;  // l-group (4 l each)
    const int sh = wid & 1;   // s-half (2 s-tiles each)

    for (int qp = 0; qp < 2; ++qp) {
        float4v acc2[2][4][2];  // [qi][li][st]

        #pragma unroll
        for (int qi = 0; qi < 2; ++qi) {
            const int qc = qp * 2 + qi;

            // ---- stage 1: Y[b][q in chunk][k] ; wave handles k in [wid*8, wid*8+8) ----
            float4v acc[8];
            #pragma unroll
            for (int j = 0; j < 8; ++j) {
                const int k = wid * 8 + j;
                const __bf16* w1p = w1b + ((k * 64 + qc * 16 + m) * 64) + quad * 8;
                bf16x8 bb0 = *(const bf16x8*)(w1p);
                bf16x8 bb1 = *(const bf16x8*)(w1p + 32);
                float4v c = {0.f, 0.f, 0.f, 0.f};
                c = __builtin_amdgcn_mfma_f32_16x16x32_bf16(xa[j][0], bb0, c, 0, 0, 0);
                c = __builtin_amdgcn_mfma_f32_16x16x32_bf16(xa[j][1], bb1, c, 0, 0, 0);
                acc[j] = c;
            }

            __syncthreads();  // previous LDS consumers done (stage-2 Y reads / O reads)

            // D: lane holds D[b = quad*4+reg][q = qc*16+m], value acc[j][reg] for k=wid*8+j.
            #pragma unroll
            for (int reg = 0; reg < 4; ++reg) {
                const int bl = quad * 4 + reg;
                const int cs = wid ^ (m & 7) ^ (bl & 7);
                bf16x8 v;
                #pragma unroll
                for (int j = 0; j < 8; ++j) v[j] = (__bf16)acc[j][reg];
                *(bf16x8*)(&Y[((bl * 16 + m) * 8 + cs) * 8]) = v;
            }
            __syncthreads();

            // ---- stage 2: l = qc*16 + lg*4 + li ; s-tiles sh*2+st -> acc2[qi] ----
            #pragma unroll
            for (int li = 0; li < 4; ++li)
                #pragma unroll
                for (int st = 0; st < 2; ++st) acc2[qi][li][st] = (float4v){0.f, 0.f, 0.f, 0.f};

            #pragma unroll
            for (int h = 0; h < 2; ++h) {
                #pragma unroll
                for (int li = 0; li < 4; ++li) {
                    const int ll = lg * 4 + li;
                    const int l  = qc * 16 + ll;
                    const int kc = h * 4 + quad;
                    const int cs = kc ^ (ll & 7) ^ (m & 7);
                    // A2[b = m][r = h*32 + quad*8 + e] = Y[b][ll][r]
                    bf16x8 a2 = *(const bf16x8*)(&Y[((m * 16 + ll) * 8 + cs) * 8]);
                    const __bf16* w2p = w2b + (l * 64) * 64 + h * 32 + quad * 8;
                    #pragma unroll
                    for (int st = 0; st < 2; ++st) {
                        const int s = (sh * 2 + st) * 16 + m;
                        bf16x8 b2 = *(const bf16x8*)(w2p + s * 64);
                        acc2[qi][li][st] = __builtin_amdgcn_mfma_f32_16x16x32_bf16(a2, b2, acc2[qi][li][st], 0, 0, 0);
                    }
                }
            }
        }

        __syncthreads();  // all waves done reading Y before O overwrites it

        // ---- epilogue: 2 rounds (by st). Round st covers s in {sh*32 + st*16 + m}.
        // O dword addr = (bl*32 + slot)*32 + phys4*4 + li,
        //   slot = m + sh*16 (s = (sh*2+st)*16+m), phys4 = ((qi<<2)|lg) ^ (m&7).
        // Write phase: per instr, 8 lanes per 4-bank group -> 8 dwords/bank (minimal).
        // Read phase: 8 consecutive slots x lanef8 -> same 8 dwords/bank.
        #pragma unroll
        for (int st = 0; st < 2; ++st) {
            if (st) __syncthreads();  // round-0 O reads done before round-1 overwrites

            const int slot = m + sh * 16;
            #pragma unroll
            for (int qi = 0; qi < 2; ++qi) {
                const int p4 = ((qi << 2) | lg) ^ (m & 7);
                #pragma unroll
                for (int reg = 0; reg < 4; ++reg) {
                    const int bl = quad * 4 + reg;
                    float4v v;
                    #pragma unroll
                    for (int li = 0; li < 4; ++li) v[li] = acc2[qi][li][st][reg];
                    *(float4v*)(&O[(bl * 32 + slot) * 32 + p4 * 4]) = v;
                }
            }
            __syncthreads();

            // coalesced read + full-line global store: 8 phases x 512 thr x float4 = 64 KiB.
            // 8 adjacent lanes cover one contiguous 128-B chunk out[b][s*64+qp*32 .. +32]
            // -> every touched L2 line fully dirtied by ONE instruction, no RMW.
            #pragma unroll
            for (int ph = 0; ph < 8; ++ph) {
                const int g      = ph * 512 + tid;
                const int lanef8 = g & 7;
                const int c      = g >> 3;       // 0..511
                const int rslot  = c & 31;
                const int bl     = c >> 5;       // 0..15
                const int phys   = (lanef8 ^ (rslot & 7)) << 2;
                float4v v = *(const float4v*)(&O[(bl * 32 + rslot) * 32 + phys]);
                const int s = ((rslot >> 4) * 2 + st) * 16 + (rslot & 15);
                float* dst = out + (long)(b0 + bl) * 4096 + s * 64 + qp * 32 + lanef8 * 4;
                __builtin_nontemporal_store(v, (float4v*)dst);
            }
        }
        // next qp's first __syncthreads protects this round's O reads
    }
}

extern "C" void kernel_launch(void* const* d_in, const int* in_sizes, int n_in,
                              void* d_out, int out_size, void* d_ws, size_t ws_size,
                              hipStream_t stream) {
    const float* x  = (const float*)d_in[0];
    const float* w1 = (const float*)d_in[1];
    const float* w2 = (const float*)d_in[2];
    float* out = (float*)d_out;
    __bf16* wb = (__bf16*)d_ws;   // w1b at [0, 262144), w2b at [262144, 524288)

    hipLaunchKernelGGL(cvt_weights, dim3(128), dim3(256), 0, stream, w1, w2, wb);
    hipLaunchKernelGGL(monarch_fused, dim3(8192 / 16), dim3(512), 0, stream,
                       x, wb, wb + 262144, out);
}